// Round 4
// baseline (185.516 us; speedup 1.0000x reference)
//
#include <hip/hip_runtime.h>
#include <math.h>

#define B_   4
#define L_   1024
#define HID_ 768
#define NH_  12
#define D_   64
#define SCALE_ 0.125f
#define NEGV (-1e15f)

typedef __attribute__((ext_vector_type(4))) float  f32x4;
typedef __attribute__((ext_vector_type(8))) __bf16 bf16x8;
typedef __attribute__((ext_vector_type(8))) unsigned short ushort8v;
typedef __attribute__((ext_vector_type(4))) unsigned short ushort4v;

typedef const __attribute__((address_space(1))) unsigned int* gas1_t;
typedef __attribute__((address_space(3))) unsigned int*       las3_t;
#define GLDS16(g, l) __builtin_amdgcn_global_load_lds((gas1_t)(g), (las3_t)(l), 16, 0, 0)

static __device__ __forceinline__ unsigned short f2bf(float f) {
    unsigned int u = __builtin_bit_cast(unsigned int, f);
    u += 0x7fffu + ((u >> 16) & 1u);           // RNE
    return (unsigned short)(u >> 16);
}

// ---------------------------------------------------------------------------
// inp f32 -> bf16 (row-major kept). n4 = elems/4.
// ---------------------------------------------------------------------------
__global__ __launch_bounds__(256) void convert_x_kernel(
    const float* __restrict__ in, unsigned short* __restrict__ out, int n4)
{
    int i = blockIdx.x * 256 + threadIdx.x;
    if (i < n4) {
        float4 v = reinterpret_cast<const float4*>(in)[i];
        ushort4v o;
        o.x = f2bf(v.x); o.y = f2bf(v.y); o.z = f2bf(v.z); o.w = f2bf(v.w);
        reinterpret_cast<ushort4v*>(out)[i] = o;
    }
}

// ---------------------------------------------------------------------------
// W f32 [768 in][768 out] -> Wt bf16 [768 out][768 in]. grid (12,12,6).
// ---------------------------------------------------------------------------
struct WArgs { const float* w[6]; unsigned short* wt[6]; };

__global__ __launch_bounds__(256) void transpose_w_kernel(WArgs a)
{
    const float* W = a.w[blockIdx.z];
    unsigned short* Wt = a.wt[blockIdx.z];
    __shared__ float t[64][65];
    const int tid = threadIdx.x;
    const int lr = tid >> 2, lc4 = (tid & 3) * 16;
    const int r0 = blockIdx.y * 64, c0 = blockIdx.x * 64;
#pragma unroll
    for (int j = 0; j < 4; ++j) {
        float4 v = *reinterpret_cast<const float4*>(&W[(size_t)(r0 + lr) * HID_ + c0 + lc4 + j * 4]);
        t[lr][lc4 + j * 4 + 0] = v.x;
        t[lr][lc4 + j * 4 + 1] = v.y;
        t[lr][lc4 + j * 4 + 2] = v.z;
        t[lr][lc4 + j * 4 + 3] = v.w;
    }
    __syncthreads();
    unsigned short tmp[16];
#pragma unroll
    for (int j = 0; j < 16; ++j) tmp[j] = f2bf(t[lc4 + j][lr]);
    unsigned short* dst = &Wt[(size_t)(c0 + lr) * HID_ + r0 + lc4];
    *reinterpret_cast<ushort8v*>(dst)     = *reinterpret_cast<ushort8v*>(&tmp[0]);
    *reinterpret_cast<ushort8v*>(dst + 8) = *reinterpret_cast<ushort8v*>(&tmp[8]);
}

// ---------------------------------------------------------------------------
// bf16 GEMM: C[M=4096, 768] = A[4096,768] @ Wt^T + bias.
// 128x128 tile, BK=32, 4 waves (2x2), 4x4 fragments of 16x16x32 MFMA.
// mode 0: f32 C[m][n] ; mode 1: bf16 C[m][n] ; mode 2: bf16 Vt[(b*768+n)*1024+l]
// ---------------------------------------------------------------------------
struct GemmJob {
    const unsigned short* A;
    const unsigned short* Wt;
    const float* bias;
    void* C;
    int mode;
    int relu;
    float scale;
};
struct GemmArgs { GemmJob j[3]; };

__global__ __launch_bounds__(256) void gemm_bf16_kernel(GemmArgs args)
{
    const GemmJob jb = args.j[blockIdx.z];
    __shared__ unsigned short As[4096];   // [128][32] bf16, chunk-swizzled
    __shared__ unsigned short Bs[4096];

    const int tid = threadIdx.x;
    const int w = tid >> 6, lane = tid & 63, g = lane >> 4, lq = lane & 15;
    const int wr = w >> 1, wc = w & 1;
    const int m0 = blockIdx.x * 128, n0 = blockIdx.y * 128;

    f32x4 acc[4][4];
#pragma unroll
    for (int i = 0; i < 4; ++i)
#pragma unroll
        for (int j = 0; j < 4; ++j) acc[i][j] = (f32x4){0.f, 0.f, 0.f, 0.f};

    const int cA0 = tid,       rA0 = cA0 >> 2, kq0 = (cA0 & 3) ^ ((rA0 >> 1) & 3);
    const int cA1 = 256 + tid, rA1 = cA1 >> 2, kq1 = (cA1 & 3) ^ ((rA1 >> 1) & 3);
    const unsigned short* Ap0 = jb.A  + (size_t)(m0 + rA0) * HID_ + kq0 * 8;
    const unsigned short* Ap1 = jb.A  + (size_t)(m0 + rA1) * HID_ + kq1 * 8;
    const unsigned short* Bp0 = jb.Wt + (size_t)(n0 + rA0) * HID_ + kq0 * 8;
    const unsigned short* Bp1 = jb.Wt + (size_t)(n0 + rA1) * HID_ + kq1 * 8;
    char* AsB = (char*)As;
    char* BsB = (char*)Bs;
    const int wb = w * 1024;

    for (int k0 = 0; k0 < HID_; k0 += 32) {
        __syncthreads();
        GLDS16(Ap0 + k0, AsB + wb);
        GLDS16(Ap1 + k0, AsB + 4096 + wb);
        GLDS16(Bp0 + k0, BsB + wb);
        GLDS16(Bp1 + k0, BsB + 4096 + wb);
        __syncthreads();

        bf16x8 af[4], bf[4];
#pragma unroll
        for (int mi = 0; mi < 4; ++mi) {
            int row = wr * 64 + mi * 16 + lq;
            int kc = (g ^ ((row >> 1) & 3)) * 8;
            af[mi] = *reinterpret_cast<const bf16x8*>(&As[row * 32 + kc]);
        }
#pragma unroll
        for (int ni = 0; ni < 4; ++ni) {
            int row = wc * 64 + ni * 16 + lq;
            int kc = (g ^ ((row >> 1) & 3)) * 8;
            bf[ni] = *reinterpret_cast<const bf16x8*>(&Bs[row * 32 + kc]);
        }
#pragma unroll
        for (int mi = 0; mi < 4; ++mi)
#pragma unroll
            for (int ni = 0; ni < 4; ++ni)
                acc[mi][ni] = __builtin_amdgcn_mfma_f32_16x16x32_bf16(
                    af[mi], bf[ni], acc[mi][ni], 0, 0, 0);
    }

    float bcol[4];
#pragma unroll
    for (int ni = 0; ni < 4; ++ni) bcol[ni] = jb.bias[n0 + wc * 64 + ni * 16 + lq];

#pragma unroll
    for (int mi = 0; mi < 4; ++mi) {
#pragma unroll
        for (int ni = 0; ni < 4; ++ni) {
            const int n = n0 + wc * 64 + ni * 16 + lq;
            float v[4];
#pragma unroll
            for (int r = 0; r < 4; ++r) {
                float x = (acc[mi][ni][r] + bcol[ni]) * jb.scale;
                if (jb.relu) x = fmaxf(x, 0.f);
                v[r] = x;
            }
            const int mbase = m0 + wr * 64 + mi * 16 + 4 * g;
            if (jb.mode == 0) {
                float* C = (float*)jb.C;
#pragma unroll
                for (int r = 0; r < 4; ++r)
                    C[(size_t)(mbase + r) * HID_ + n] = v[r];
            } else if (jb.mode == 1) {
                unsigned short* C = (unsigned short*)jb.C;
#pragma unroll
                for (int r = 0; r < 4; ++r)
                    C[(size_t)(mbase + r) * HID_ + n] = f2bf(v[r]);
            } else {
                unsigned short* C = (unsigned short*)jb.C;
                const int bb = mbase >> 10, ltok = mbase & 1023;
                ushort4v o;
                o.x = f2bf(v[0]); o.y = f2bf(v[1]); o.z = f2bf(v[2]); o.w = f2bf(v[3]);
                *reinterpret_cast<ushort4v*>(&C[(size_t)(bb * HID_ + n) * L_ + ltok]) = o;
            }
        }
    }
}

// ---------------------------------------------------------------------------
// Flash attention, bf16 MFMA, split-KV across waves:
//  - wave w handles k-tiles {w, w+4, w+8, w+12} ∩ [0, nkt) — serial chain /4
//  - NO barriers in the k-loop; K/V fragments read directly from global (L2)
//  - per-wave-private P staging in LDS; 4-way flash-state merge at the end
// Q pre-scaled. Vt layout [b][h][d][l]. Grid (16, 48), 256 thr = 4 waves.
// ---------------------------------------------------------------------------
__global__ __launch_bounds__(256, 2) void attn_mfma_kernel(
    const unsigned short* __restrict__ Qb, const unsigned short* __restrict__ Kb,
    const unsigned short* __restrict__ Vtb, const float* __restrict__ rel,
    const int* __restrict__ seq_len, const int* __restrict__ lex_num,
    unsigned short* __restrict__ ctx)
{
    const int qt = blockIdx.x, bh = blockIdx.y;
    const int b = bh / NH_, h = bh % NH_;
    const int q0 = qt * 64;
    const int sl = seq_len[b] + lex_num[0];
    const int nkt = (sl + 63) >> 6;

    // 36864 B: per-wave P staging [64][72] bf16; reused as two f32 merge bufs
    __shared__ __align__(16) char shraw[36864];
    __shared__ float mlbuf[4][64][2];

    const int tid = threadIdx.x;
    const int w = tid >> 6, lane = tid & 63, g = lane >> 4, lq = lane & 15;
    unsigned short* Psw = reinterpret_cast<unsigned short*>(shraw) + w * 4608;

    // Q A-fragments in registers: aq[qi][ks] = Q[q0+qi*16+lq][ks*32+g*8 ..]
    bf16x8 aq[4][2];
#pragma unroll
    for (int qi = 0; qi < 4; ++qi)
#pragma unroll
        for (int ks = 0; ks < 2; ++ks)
            aq[qi][ks] = *reinterpret_cast<const bf16x8*>(
                &Qb[(size_t)(b * L_ + q0 + qi * 16 + lq) * HID_ + h * D_ + ks * 32 + g * 8]);

    f32x4 acc[4][4];
    float m_s[4][4], l_s[4][4];
#pragma unroll
    for (int qi = 0; qi < 4; ++qi)
#pragma unroll
        for (int j = 0; j < 4; ++j) {
            acc[qi][j] = (f32x4){0.f, 0.f, 0.f, 0.f};
            m_s[qi][j] = -3e38f; l_s[qi][j] = 0.f;
        }

    const float* relp = rel + (size_t)bh * (L_ * L_) + (size_t)(q0 + 4 * g) * L_ + lq;

    for (int kt = w; kt < nkt; kt += 4) {
        const int k0 = kt * 64;

        // K/V B-fragments straight from global
        bf16x8 bk[4][2], bv[4][2];
#pragma unroll
        for (int ni = 0; ni < 4; ++ni)
#pragma unroll
            for (int ks = 0; ks < 2; ++ks) {
                bk[ni][ks] = *reinterpret_cast<const bf16x8*>(
                    &Kb[(size_t)(b * L_ + k0 + ni * 16 + lq) * HID_ + h * D_ + ks * 32 + g * 8]);
                bv[ni][ks] = *reinterpret_cast<const bf16x8*>(
                    &Vtb[(size_t)(b * HID_ + h * D_ + ni * 16 + lq) * L_ + k0 + ks * 32 + g * 8]);
            }

        // rel for qi=0 (ping-pong one qi ahead)
        float rvA[16], rvB[16];
#pragma unroll
        for (int ni = 0; ni < 4; ++ni)
#pragma unroll
            for (int r = 0; r < 4; ++r)
                rvA[ni * 4 + r] = relp[(size_t)(0 * 16 + r) * L_ + k0 + ni * 16];

#pragma unroll
        for (int qi = 0; qi < 4; ++qi) {
            float* rvc = (qi & 1) ? rvB : rvA;
            float* rvn = (qi & 1) ? rvA : rvB;
            if (qi < 3) {
#pragma unroll
                for (int ni = 0; ni < 4; ++ni)
#pragma unroll
                    for (int r = 0; r < 4; ++r)
                        rvn[ni * 4 + r] = relp[(size_t)((qi + 1) * 16 + r) * L_ + k0 + ni * 16];
            }

            // S sub-strip: rows qi*16+4g+r, cols ni*16+lq
            f32x4 s[4];
#pragma unroll
            for (int ni = 0; ni < 4; ++ni) s[ni] = (f32x4){0.f, 0.f, 0.f, 0.f};
#pragma unroll
            for (int ks = 0; ks < 2; ++ks)
#pragma unroll
                for (int ni = 0; ni < 4; ++ni)
                    s[ni] = __builtin_amdgcn_mfma_f32_16x16x32_bf16(
                        aq[qi][ks], bk[ni][ks], s[ni], 0, 0, 0);

            float sv[4][4];
#pragma unroll
            for (int ni = 0; ni < 4; ++ni) {
                const int col = k0 + ni * 16 + lq;
                const bool ok = col < sl;
#pragma unroll
                for (int r = 0; r < 4; ++r)
                    sv[ni][r] = ok ? (s[ni][r] + rvc[ni * 4 + r]) : NEGV;
            }

            // online softmax per row (16 lanes of lq share a row)
#pragma unroll
            for (int r = 0; r < 4; ++r) {
                float rm = fmaxf(fmaxf(sv[0][r], sv[1][r]), fmaxf(sv[2][r], sv[3][r]));
                rm = fmaxf(rm, __shfl_xor(rm, 1, 16));
                rm = fmaxf(rm, __shfl_xor(rm, 2, 16));
                rm = fmaxf(rm, __shfl_xor(rm, 4, 16));
                rm = fmaxf(rm, __shfl_xor(rm, 8, 16));
                float mn = fmaxf(m_s[qi][r], rm);
                float sc = __expf(m_s[qi][r] - mn);
                float p[4], rs = 0.f;
#pragma unroll
                for (int ni = 0; ni < 4; ++ni) {
                    p[ni] = __expf(sv[ni][r] - mn);
                    rs += p[ni];
                }
                rs += __shfl_xor(rs, 1, 16);
                rs += __shfl_xor(rs, 2, 16);
                rs += __shfl_xor(rs, 4, 16);
                rs += __shfl_xor(rs, 8, 16);
                l_s[qi][r] = l_s[qi][r] * sc + rs;
                m_s[qi][r] = mn;
#pragma unroll
                for (int ni = 0; ni < 4; ++ni) {
                    acc[qi][ni][r] *= sc;
                    Psw[(qi * 16 + 4 * g + r) * 72 + ni * 16 + lq] = f2bf(p[ni]);
                }
            }

            // PV for this qi (same-wave LDS round trip, no barrier)
#pragma unroll
            for (int ks = 0; ks < 2; ++ks) {
                bf16x8 ap = *reinterpret_cast<const bf16x8*>(
                    &Psw[(qi * 16 + lq) * 72 + ks * 32 + g * 8]);
#pragma unroll
                for (int ni = 0; ni < 4; ++ni)
                    acc[qi][ni] = __builtin_amdgcn_mfma_f32_16x16x32_bf16(
                        ap, bv[ni][ks], acc[qi][ni], 0, 0, 0);
            }
        }
    }

    // ---- merge the 4 waves' partial flash states ----
    if (lq == 0) {
#pragma unroll
        for (int qi = 0; qi < 4; ++qi)
#pragma unroll
            for (int r = 0; r < 4; ++r) {
                const int row = qi * 16 + 4 * g + r;
                mlbuf[w][row][0] = m_s[qi][r];
                mlbuf[w][row][1] = l_s[qi][r];
            }
    }
    __syncthreads();

    // global max / sum per row; scale own acc by exp(m_w - M)
    float Lrow[4][4];
#pragma unroll
    for (int qi = 0; qi < 4; ++qi)
#pragma unroll
        for (int r = 0; r < 4; ++r) {
            const int row = qi * 16 + 4 * g + r;
            float m0 = mlbuf[0][row][0], m1 = mlbuf[1][row][0];
            float m2 = mlbuf[2][row][0], m3 = mlbuf[3][row][0];
            float M = fmaxf(fmaxf(m0, m1), fmaxf(m2, m3));
            float L = mlbuf[0][row][1] * __expf(m0 - M)
                    + mlbuf[1][row][1] * __expf(m1 - M)
                    + mlbuf[2][row][1] * __expf(m2 - M)
                    + mlbuf[3][row][1] * __expf(m3 - M);
            Lrow[qi][r] = L;
            float alpha = __expf(m_s[qi][r] - M);
#pragma unroll
            for (int ni = 0; ni < 4; ++ni) acc[qi][ni][r] *= alpha;
        }

    // tree-sum acc through LDS (reuse P region): bufT[d][q] f32, stride 68
    float* bufA = reinterpret_cast<float*>(shraw);
    float* bufB = reinterpret_cast<float*>(shraw + 17408);
    if (w == 1 || w == 3) {
        float* buf = (w == 1) ? bufA : bufB;
#pragma unroll
        for (int qi = 0; qi < 4; ++qi)
#pragma unroll
            for (int ni = 0; ni < 4; ++ni)
                *reinterpret_cast<f32x4*>(&buf[(ni * 16 + lq) * 68 + qi * 16 + 4 * g]) = acc[qi][ni];
    }
    __syncthreads();
    if (w == 0) {
#pragma unroll
        for (int qi = 0; qi < 4; ++qi)
#pragma unroll
            for (int ni = 0; ni < 4; ++ni)
                acc[qi][ni] += *reinterpret_cast<f32x4*>(&bufA[(ni * 16 + lq) * 68 + qi * 16 + 4 * g]);
    }
    if (w == 2) {
#pragma unroll
        for (int qi = 0; qi < 4; ++qi)
#pragma unroll
            for (int ni = 0; ni < 4; ++ni) {
                acc[qi][ni] += *reinterpret_cast<f32x4*>(&bufB[(ni * 16 + lq) * 68 + qi * 16 + 4 * g]);
                *reinterpret_cast<f32x4*>(&bufB[(ni * 16 + lq) * 68 + qi * 16 + 4 * g]) = acc[qi][ni];
            }
    }
    __syncthreads();
    if (w == 0) {
#pragma unroll
        for (int qi = 0; qi < 4; ++qi) {
            float invl[4];
#pragma unroll
            for (int r = 0; r < 4; ++r) invl[r] = 1.f / Lrow[qi][r];
#pragma unroll
            for (int ni = 0; ni < 4; ++ni) {
                f32x4 v = acc[qi][ni] +
                    *reinterpret_cast<f32x4*>(&bufB[(ni * 16 + lq) * 68 + qi * 16 + 4 * g]);
#pragma unroll
                for (int r = 0; r < 4; ++r)
                    ctx[(size_t)(b * L_ + q0 + qi * 16 + 4 * g + r) * HID_ + h * D_ + ni * 16 + lq] =
                        f2bf(v[r] * invl[r]);
            }
        }
    }
}

// ---------------------------------------------------------------------------
// LayerNorm(2*x) over rows of 768; out f32 or bf16.
// ---------------------------------------------------------------------------
__global__ __launch_bounds__(256) void ln2_kernel(
    const float* __restrict__ in, const float* __restrict__ g,
    const float* __restrict__ bta, void* __restrict__ out, int bf16out)
{
    const int row = blockIdx.x;
    const float* x = in + (size_t)row * HID_;
    const int tid = threadIdx.x;

    float vals[3];
    float s = 0.f, ss = 0.f;
#pragma unroll
    for (int j = 0; j < 3; ++j) {
        float t = 2.f * x[tid + j * 256];
        vals[j] = t;
        s += t;
        ss += t * t;
    }
#pragma unroll
    for (int m = 1; m < 64; m <<= 1) {
        s += __shfl_xor(s, m, 64);
        ss += __shfl_xor(ss, m, 64);
    }
    __shared__ float sb[4], ssb[4];
    if ((tid & 63) == 0) { sb[tid >> 6] = s; ssb[tid >> 6] = ss; }
    __syncthreads();
    s = sb[0] + sb[1] + sb[2] + sb[3];
    ss = ssb[0] + ssb[1] + ssb[2] + ssb[3];
    const float mean = s * (1.f / 768.f);
    float var = ss * (1.f / 768.f) - mean * mean;
    if (var < 0.f) var = 0.f;
    const float invs = rsqrtf(var + 1e-5f);
    if (bf16out) {
        unsigned short* o = (unsigned short*)out;
#pragma unroll
        for (int j = 0; j < 3; ++j) {
            int c = tid + j * 256;
            o[(size_t)row * HID_ + c] = f2bf((vals[j] - mean) * invs * g[c] + bta[c]);
        }
    } else {
        float* o = (float*)out;
#pragma unroll
        for (int j = 0; j < 3; ++j) {
            int c = tid + j * 256;
            o[(size_t)row * HID_ + c] = (vals[j] - mean) * invs * g[c] + bta[c];
        }
    }
}

// ---------------------------------------------------------------------------
extern "C" void kernel_launch(void* const* d_in, const int* in_sizes, int n_in,
                              void* d_out, int out_size, void* d_ws, size_t ws_size,
                              hipStream_t stream) {
    const float* inp     = (const float*)d_in[0];
    const int*   seq_len = (const int*)d_in[1];
    const int*   lex_num = (const int*)d_in[2];
    const float* rel     = (const float*)d_in[3];
    const float* Wq = (const float*)d_in[4];
    const float* bq = (const float*)d_in[5];
    const float* Wk = (const float*)d_in[6];
    const float* bk = (const float*)d_in[7];
    const float* Wv = (const float*)d_in[8];
    const float* bv = (const float*)d_in[9];
    const float* Wo = (const float*)d_in[10];
    const float* bo = (const float*)d_in[11];
    const float* W0 = (const float*)d_in[12];
    const float* b0 = (const float*)d_in[13];
    const float* W1 = (const float*)d_in[14];
    const float* b1 = (const float*)d_in[15];
    const float* ln_g = (const float*)d_in[16];
    const float* ln_b = (const float*)d_in[17];
    float* out = (float*)d_out;

    // ---- workspace carve (bytes) ----
    char* W = (char*)d_ws;
    const size_t WT_SZ = (size_t)HID_ * HID_ * 2;
    unsigned short* Wt[6];
    for (int i = 0; i < 6; ++i) Wt[i] = (unsigned short*)(W + i * WT_SZ);
    size_t off = 6 * WT_SZ;
    const size_t TOK_BF = (size_t)B_ * L_ * HID_ * 2;
    unsigned short* qb  = (unsigned short*)(W + off); off += TOK_BF;
    unsigned short* kb  = (unsigned short*)(W + off); off += TOK_BF;
    unsigned short* vtb = (unsigned short*)(W + off); off += TOK_BF;
    unsigned short* Eb  = (unsigned short*)(W + off); off += TOK_BF;
    float* Fbuf = (float*)(W + off);

    unsigned short* Xb   = Eb;
    unsigned short* ctxb = Eb;
    unsigned short* y2b  = vtb;
    unsigned short* hb   = qb;

    convert_x_kernel<<<dim3(3072), dim3(256), 0, stream>>>(inp, Xb, (B_ * L_ * HID_) / 4);

    {
        WArgs wa;
        const float* ws_[6] = {Wq, Wk, Wv, Wo, W0, W1};
        for (int i = 0; i < 6; ++i) { wa.w[i] = ws_[i]; wa.wt[i] = Wt[i]; }
        transpose_w_kernel<<<dim3(12, 12, 6), dim3(256), 0, stream>>>(wa);
    }

    {
        GemmArgs ga;
        ga.j[0] = {Xb, Wt[0], bq, (void*)qb,  1, 0, SCALE_};
        ga.j[1] = {Xb, Wt[1], bk, (void*)kb,  1, 0, 1.f};
        ga.j[2] = {Xb, Wt[2], bv, (void*)vtb, 2, 0, 1.f};
        gemm_bf16_kernel<<<dim3(32, 6, 3), dim3(256), 0, stream>>>(ga);
    }

    attn_mfma_kernel<<<dim3(16, 48), dim3(256), 0, stream>>>(
        qb, kb, vtb, rel, seq_len, lex_num, ctxb);

    {
        GemmArgs ga;
        ga.j[0] = {ctxb, Wt[3], bo, (void*)Fbuf, 0, 0, 1.f};
        gemm_bf16_kernel<<<dim3(32, 6, 1), dim3(256), 0, stream>>>(ga);
    }
    ln2_kernel<<<dim3(4096), dim3(256), 0, stream>>>(Fbuf, ln_g, ln_b, (void*)y2b, 1);
    {
        GemmArgs ga;
        ga.j[0] = {y2b, Wt[4], b0, (void*)hb, 1, 1, 1.f};
        gemm_bf16_kernel<<<dim3(32, 6, 1), dim3(256), 0, stream>>>(ga);
    }
    {
        GemmArgs ga;
        ga.j[0] = {hb, Wt[5], b1, (void*)Fbuf, 0, 0, 1.f};
        gemm_bf16_kernel<<<dim3(32, 6, 1), dim3(256), 0, stream>>>(ga);
    }
    ln2_kernel<<<dim3(4096), dim3(256), 0, stream>>>(Fbuf, ln_g, ln_b, (void*)out, 0);
}

// Round 5
// 157.722 us; speedup vs baseline: 1.1762x; 1.1762x over previous
//
#include <hip/hip_runtime.h>
#include <math.h>

#define B_   4
#define L_   1024
#define HID_ 768
#define NH_  12
#define D_   64
#define SCALE_ 0.125f
#define NEGV (-1e15f)

typedef __attribute__((ext_vector_type(4))) float  f32x4;
typedef __attribute__((ext_vector_type(8))) __bf16 bf16x8;
typedef __attribute__((ext_vector_type(8))) unsigned short ushort8v;
typedef __attribute__((ext_vector_type(4))) unsigned short ushort4v;

typedef const __attribute__((address_space(1))) unsigned int* gas1_t;
typedef __attribute__((address_space(3))) unsigned int*       las3_t;
#define GLDS16(g, l) __builtin_amdgcn_global_load_lds((gas1_t)(g), (las3_t)(l), 16, 0, 0)

static __device__ __forceinline__ unsigned short f2bf(float f) {
    unsigned int u = __builtin_bit_cast(unsigned int, f);
    u += 0x7fffu + ((u >> 16) & 1u);           // RNE
    return (unsigned short)(u >> 16);
}

// ---------------------------------------------------------------------------
// inp f32 -> bf16 (row-major kept). n4 = elems/4.
// ---------------------------------------------------------------------------
__global__ __launch_bounds__(256) void convert_x_kernel(
    const float* __restrict__ in, unsigned short* __restrict__ out, int n4)
{
    int i = blockIdx.x * 256 + threadIdx.x;
    if (i < n4) {
        float4 v = reinterpret_cast<const float4*>(in)[i];
        ushort4v o;
        o.x = f2bf(v.x); o.y = f2bf(v.y); o.z = f2bf(v.z); o.w = f2bf(v.w);
        reinterpret_cast<ushort4v*>(out)[i] = o;
    }
}

// ---------------------------------------------------------------------------
// W f32 [768 in][768 out] -> Wt bf16 [768 out][768 in]. grid (12,12,6).
// ---------------------------------------------------------------------------
struct WArgs { const float* w[6]; unsigned short* wt[6]; };

__global__ __launch_bounds__(256) void transpose_w_kernel(WArgs a)
{
    const float* W = a.w[blockIdx.z];
    unsigned short* Wt = a.wt[blockIdx.z];
    __shared__ float t[64][65];
    const int tid = threadIdx.x;
    const int lr = tid >> 2, lc4 = (tid & 3) * 16;
    const int r0 = blockIdx.y * 64, c0 = blockIdx.x * 64;
#pragma unroll
    for (int j = 0; j < 4; ++j) {
        float4 v = *reinterpret_cast<const float4*>(&W[(size_t)(r0 + lr) * HID_ + c0 + lc4 + j * 4]);
        t[lr][lc4 + j * 4 + 0] = v.x;
        t[lr][lc4 + j * 4 + 1] = v.y;
        t[lr][lc4 + j * 4 + 2] = v.z;
        t[lr][lc4 + j * 4 + 3] = v.w;
    }
    __syncthreads();
    unsigned short tmp[16];
#pragma unroll
    for (int j = 0; j < 16; ++j) tmp[j] = f2bf(t[lc4 + j][lr]);
    unsigned short* dst = &Wt[(size_t)(c0 + lr) * HID_ + r0 + lc4];
    *reinterpret_cast<ushort8v*>(dst)     = *reinterpret_cast<ushort8v*>(&tmp[0]);
    *reinterpret_cast<ushort8v*>(dst + 8) = *reinterpret_cast<ushort8v*>(&tmp[8]);
}

// ---------------------------------------------------------------------------
// bf16 GEMM: C[M=4096, 768] = A[4096,768] @ Wt^T + bias.
// 128x128 tile, BK=32, 4 waves (2x2), 4x4 fragments of 16x16x32 MFMA.
// mode 0: f32 C[m][n] ; mode 1: bf16 C[m][n] ; mode 2: bf16 Vt[(b*768+n)*1024+l]
// ---------------------------------------------------------------------------
struct GemmJob {
    const unsigned short* A;
    const unsigned short* Wt;
    const float* bias;
    void* C;
    int mode;
    int relu;
    float scale;
};
struct GemmArgs { GemmJob j[3]; };

__global__ __launch_bounds__(256) void gemm_bf16_kernel(GemmArgs args)
{
    const GemmJob jb = args.j[blockIdx.z];
    __shared__ unsigned short As[4096];   // [128][32] bf16, chunk-swizzled
    __shared__ unsigned short Bs[4096];

    const int tid = threadIdx.x;
    const int w = tid >> 6, lane = tid & 63, g = lane >> 4, lq = lane & 15;
    const int wr = w >> 1, wc = w & 1;
    const int m0 = blockIdx.x * 128, n0 = blockIdx.y * 128;

    f32x4 acc[4][4];
#pragma unroll
    for (int i = 0; i < 4; ++i)
#pragma unroll
        for (int j = 0; j < 4; ++j) acc[i][j] = (f32x4){0.f, 0.f, 0.f, 0.f};

    const int cA0 = tid,       rA0 = cA0 >> 2, kq0 = (cA0 & 3) ^ ((rA0 >> 1) & 3);
    const int cA1 = 256 + tid, rA1 = cA1 >> 2, kq1 = (cA1 & 3) ^ ((rA1 >> 1) & 3);
    const unsigned short* Ap0 = jb.A  + (size_t)(m0 + rA0) * HID_ + kq0 * 8;
    const unsigned short* Ap1 = jb.A  + (size_t)(m0 + rA1) * HID_ + kq1 * 8;
    const unsigned short* Bp0 = jb.Wt + (size_t)(n0 + rA0) * HID_ + kq0 * 8;
    const unsigned short* Bp1 = jb.Wt + (size_t)(n0 + rA1) * HID_ + kq1 * 8;
    char* AsB = (char*)As;
    char* BsB = (char*)Bs;
    const int wb = w * 1024;

    for (int k0 = 0; k0 < HID_; k0 += 32) {
        __syncthreads();
        GLDS16(Ap0 + k0, AsB + wb);
        GLDS16(Ap1 + k0, AsB + 4096 + wb);
        GLDS16(Bp0 + k0, BsB + wb);
        GLDS16(Bp1 + k0, BsB + 4096 + wb);
        __syncthreads();

        bf16x8 af[4], bf[4];
#pragma unroll
        for (int mi = 0; mi < 4; ++mi) {
            int row = wr * 64 + mi * 16 + lq;
            int kc = (g ^ ((row >> 1) & 3)) * 8;
            af[mi] = *reinterpret_cast<const bf16x8*>(&As[row * 32 + kc]);
        }
#pragma unroll
        for (int ni = 0; ni < 4; ++ni) {
            int row = wc * 64 + ni * 16 + lq;
            int kc = (g ^ ((row >> 1) & 3)) * 8;
            bf[ni] = *reinterpret_cast<const bf16x8*>(&Bs[row * 32 + kc]);
        }
#pragma unroll
        for (int mi = 0; mi < 4; ++mi)
#pragma unroll
            for (int ni = 0; ni < 4; ++ni)
                acc[mi][ni] = __builtin_amdgcn_mfma_f32_16x16x32_bf16(
                    af[mi], bf[ni], acc[mi][ni], 0, 0, 0);
    }

    float bcol[4];
#pragma unroll
    for (int ni = 0; ni < 4; ++ni) bcol[ni] = jb.bias[n0 + wc * 64 + ni * 16 + lq];

#pragma unroll
    for (int mi = 0; mi < 4; ++mi) {
#pragma unroll
        for (int ni = 0; ni < 4; ++ni) {
            const int n = n0 + wc * 64 + ni * 16 + lq;
            float v[4];
#pragma unroll
            for (int r = 0; r < 4; ++r) {
                float x = (acc[mi][ni][r] + bcol[ni]) * jb.scale;
                if (jb.relu) x = fmaxf(x, 0.f);
                v[r] = x;
            }
            const int mbase = m0 + wr * 64 + mi * 16 + 4 * g;
            if (jb.mode == 0) {
                float* C = (float*)jb.C;
#pragma unroll
                for (int r = 0; r < 4; ++r)
                    C[(size_t)(mbase + r) * HID_ + n] = v[r];
            } else if (jb.mode == 1) {
                unsigned short* C = (unsigned short*)jb.C;
#pragma unroll
                for (int r = 0; r < 4; ++r)
                    C[(size_t)(mbase + r) * HID_ + n] = f2bf(v[r]);
            } else {
                unsigned short* C = (unsigned short*)jb.C;
                const int bb = mbase >> 10, ltok = mbase & 1023;
                ushort4v o;
                o.x = f2bf(v[0]); o.y = f2bf(v[1]); o.z = f2bf(v[2]); o.w = f2bf(v[3]);
                *reinterpret_cast<ushort4v*>(&C[(size_t)(bb * HID_ + n) * L_ + ltok]) = o;
            }
        }
    }
}

// ---------------------------------------------------------------------------
// Flash attention, bf16 MFMA. Round-3 skeleton + coalesced rel staging:
//  - skips fully-masked key tiles (tile-skip via nkt)
//  - K/V/rel single-buffered in LDS, reg-staged one tile ahead (coalesced:
//    rel is loaded as float4 with 256B-contiguous row segments)
//  - two barriers per tile (write->A->compute->B)
// Q pre-scaled, held in registers. Vt layout [b][h][d][l]. Grid (16, 48).
// ---------------------------------------------------------------------------
__global__ __launch_bounds__(256) void attn_mfma_kernel(
    const unsigned short* __restrict__ Qb, const unsigned short* __restrict__ Kb,
    const unsigned short* __restrict__ Vtb, const float* __restrict__ rel,
    const int* __restrict__ seq_len, const int* __restrict__ lex_num,
    unsigned short* __restrict__ ctx)
{
    const int qt = blockIdx.x, bh = blockIdx.y;
    const int b = bh / NH_, h = bh % NH_;
    const int q0 = qt * 64;
    const int sl = seq_len[b] + lex_num[0];
    const int nkt = (sl + 63) >> 6;          // only tiles with >=1 valid col

    __shared__ unsigned short Ks[64 * 72];   // [k][d]   bf16
    __shared__ unsigned short Vs[64 * 72];   // [d][k]   bf16 (transposed V)
    __shared__ unsigned short Ps[64 * 72];   // [q][k]   bf16, per-wave strips
    __shared__ float          RelS[64 * 68]; // [q][k]   f32 rel tile

    const int tid = threadIdx.x;
    const int w = tid >> 6, lane = tid & 63, g = lane >> 4, lq = lane & 15;

    // K/V staging map: chunk -> (row, col-chunk of 8 elems)
    const int r0 = tid >> 3, cc0 = tid & 7;
    const int r1 = 32 + r0;
    const unsigned short* Kbase = Kb  + (size_t)(b * L_) * HID_ + h * D_;
    const unsigned short* Vbase = Vtb + (size_t)(b * HID_ + h * D_) * L_;
    // rel staging: rows w*16 + j*4 + g (j=0..3), cols lq*4 .. lq*4+3 (coalesced 256B/row)
    const float* Rstage = rel + (size_t)bh * (L_ * L_) + (size_t)(q0 + w * 16 + g) * L_ + lq * 4;

    // Q A-fragments in registers (rows w*16+lq)
    bf16x8 aq[2];
#pragma unroll
    for (int ks = 0; ks < 2; ++ks)
        aq[ks] = *reinterpret_cast<const bf16x8*>(
            &Qb[(size_t)(b * L_ + q0 + w * 16 + lq) * HID_ + h * D_ + ks * 32 + g * 8]);

    f32x4 acc[4];
    float m_r[4], l_r[4];
#pragma unroll
    for (int i = 0; i < 4; ++i) {
        acc[i] = (f32x4){0.f, 0.f, 0.f, 0.f};
        m_r[i] = -3e38f; l_r[i] = 0.f;
    }

    // prologue: stage tile 0 into regs
    ushort8v kreg0, kreg1, vreg0, vreg1;
    float4 rreg0, rreg1, rreg2, rreg3;
    kreg0 = *reinterpret_cast<const ushort8v*>(&Kbase[(size_t)r0 * HID_ + cc0 * 8]);
    kreg1 = *reinterpret_cast<const ushort8v*>(&Kbase[(size_t)r1 * HID_ + cc0 * 8]);
    vreg0 = *reinterpret_cast<const ushort8v*>(&Vbase[(size_t)r0 * L_ + cc0 * 8]);
    vreg1 = *reinterpret_cast<const ushort8v*>(&Vbase[(size_t)r1 * L_ + cc0 * 8]);
    rreg0 = *reinterpret_cast<const float4*>(&Rstage[(size_t)0  * L_]);
    rreg1 = *reinterpret_cast<const float4*>(&Rstage[(size_t)4  * L_]);
    rreg2 = *reinterpret_cast<const float4*>(&Rstage[(size_t)8  * L_]);
    rreg3 = *reinterpret_cast<const float4*>(&Rstage[(size_t)12 * L_]);

    for (int kt = 0; kt < nkt; ++kt) {
        const int k0 = kt * 64;

        // write staged regs into LDS
        *reinterpret_cast<ushort8v*>(&Ks[r0 * 72 + cc0 * 8]) = kreg0;
        *reinterpret_cast<ushort8v*>(&Ks[r1 * 72 + cc0 * 8]) = kreg1;
        *reinterpret_cast<ushort8v*>(&Vs[r0 * 72 + cc0 * 8]) = vreg0;
        *reinterpret_cast<ushort8v*>(&Vs[r1 * 72 + cc0 * 8]) = vreg1;
        *reinterpret_cast<float4*>(&RelS[(w * 16 + 0  + g) * 68 + lq * 4]) = rreg0;
        *reinterpret_cast<float4*>(&RelS[(w * 16 + 4  + g) * 68 + lq * 4]) = rreg1;
        *reinterpret_cast<float4*>(&RelS[(w * 16 + 8  + g) * 68 + lq * 4]) = rreg2;
        *reinterpret_cast<float4*>(&RelS[(w * 16 + 12 + g) * 68 + lq * 4]) = rreg3;
        __syncthreads();   // A: tile visible

        // issue next tile's global loads (land during this tile's compute)
        if (kt + 1 < nkt) {
            const int k0n = k0 + 64;
            kreg0 = *reinterpret_cast<const ushort8v*>(&Kbase[(size_t)(k0n + r0) * HID_ + cc0 * 8]);
            kreg1 = *reinterpret_cast<const ushort8v*>(&Kbase[(size_t)(k0n + r1) * HID_ + cc0 * 8]);
            vreg0 = *reinterpret_cast<const ushort8v*>(&Vbase[(size_t)r0 * L_ + k0n + cc0 * 8]);
            vreg1 = *reinterpret_cast<const ushort8v*>(&Vbase[(size_t)r1 * L_ + k0n + cc0 * 8]);
            rreg0 = *reinterpret_cast<const float4*>(&Rstage[(size_t)0  * L_ + k0n]);
            rreg1 = *reinterpret_cast<const float4*>(&Rstage[(size_t)4  * L_ + k0n]);
            rreg2 = *reinterpret_cast<const float4*>(&Rstage[(size_t)8  * L_ + k0n]);
            rreg3 = *reinterpret_cast<const float4*>(&Rstage[(size_t)12 * L_ + k0n]);
        }

        // S strip = Q strip @ K^T
        f32x4 s[4];
#pragma unroll
        for (int ni = 0; ni < 4; ++ni) s[ni] = (f32x4){0.f, 0.f, 0.f, 0.f};
#pragma unroll
        for (int ks = 0; ks < 2; ++ks) {
#pragma unroll
            for (int ni = 0; ni < 4; ++ni) {
                bf16x8 bk = *reinterpret_cast<const bf16x8*>(
                    &Ks[(ni * 16 + lq) * 72 + ks * 32 + g * 8]);
                s[ni] = __builtin_amdgcn_mfma_f32_16x16x32_bf16(aq[ks], bk, s[ni], 0, 0, 0);
            }
        }

        // + rel bias (from LDS), mask
        float sv[4][4];
#pragma unroll
        for (int ni = 0; ni < 4; ++ni) {
            const int col = k0 + ni * 16 + lq;
            const bool ok = col < sl;
#pragma unroll
            for (int r = 0; r < 4; ++r) {
                float rv = RelS[(w * 16 + 4 * g + r) * 68 + ni * 16 + lq];
                sv[ni][r] = ok ? (s[ni][r] + rv) : NEGV;
            }
        }

        // online softmax per row (16 lanes share a row)
#pragma unroll
        for (int r = 0; r < 4; ++r) {
            float rm = fmaxf(fmaxf(sv[0][r], sv[1][r]), fmaxf(sv[2][r], sv[3][r]));
            rm = fmaxf(rm, __shfl_xor(rm, 1, 16));
            rm = fmaxf(rm, __shfl_xor(rm, 2, 16));
            rm = fmaxf(rm, __shfl_xor(rm, 4, 16));
            rm = fmaxf(rm, __shfl_xor(rm, 8, 16));
            float mn = fmaxf(m_r[r], rm);
            float sc = __expf(m_r[r] - mn);
            float p[4], rs = 0.f;
#pragma unroll
            for (int ni = 0; ni < 4; ++ni) {
                p[ni] = __expf(sv[ni][r] - mn);
                rs += p[ni];
            }
            rs += __shfl_xor(rs, 1, 16);
            rs += __shfl_xor(rs, 2, 16);
            rs += __shfl_xor(rs, 4, 16);
            rs += __shfl_xor(rs, 8, 16);
            l_r[r] = l_r[r] * sc + rs;
            m_r[r] = mn;
#pragma unroll
            for (int ni = 0; ni < 4; ++ni) {
                acc[ni][r] *= sc;
                Ps[(w * 16 + 4 * g + r) * 72 + ni * 16 + lq] = f2bf(p[ni]);
            }
        }

        // O strip += P strip @ V tile (own-wave P strip, no barrier needed)
#pragma unroll
        for (int ks = 0; ks < 2; ++ks) {
            bf16x8 ap = *reinterpret_cast<const bf16x8*>(
                &Ps[(w * 16 + lq) * 72 + ks * 32 + g * 8]);
#pragma unroll
            for (int ni = 0; ni < 4; ++ni) {
                bf16x8 bv = *reinterpret_cast<const bf16x8*>(
                    &Vs[(ni * 16 + lq) * 72 + ks * 32 + g * 8]);
                acc[ni] = __builtin_amdgcn_mfma_f32_16x16x32_bf16(ap, bv, acc[ni], 0, 0, 0);
            }
        }
        __syncthreads();   // B: all waves done reading Ks/Vs/RelS
    }

    // epilogue
    float inv[4];
#pragma unroll
    for (int r = 0; r < 4; ++r) inv[r] = 1.f / l_r[r];
#pragma unroll
    for (int ni = 0; ni < 4; ++ni)
#pragma unroll
        for (int r = 0; r < 4; ++r)
            ctx[(size_t)(b * L_ + q0 + w * 16 + 4 * g + r) * HID_ + h * D_ + ni * 16 + lq] =
                f2bf(acc[ni][r] * inv[r]);
}

// ---------------------------------------------------------------------------
// LayerNorm(2*x) over rows of 768; out f32 or bf16.
// ---------------------------------------------------------------------------
__global__ __launch_bounds__(256) void ln2_kernel(
    const float* __restrict__ in, const float* __restrict__ g,
    const float* __restrict__ bta, void* __restrict__ out, int bf16out)
{
    const int row = blockIdx.x;
    const float* x = in + (size_t)row * HID_;
    const int tid = threadIdx.x;

    float vals[3];
    float s = 0.f, ss = 0.f;
#pragma unroll
    for (int j = 0; j < 3; ++j) {
        float t = 2.f * x[tid + j * 256];
        vals[j] = t;
        s += t;
        ss += t * t;
    }
#pragma unroll
    for (int m = 1; m < 64; m <<= 1) {
        s += __shfl_xor(s, m, 64);
        ss += __shfl_xor(ss, m, 64);
    }
    __shared__ float sb[4], ssb[4];
    if ((tid & 63) == 0) { sb[tid >> 6] = s; ssb[tid >> 6] = ss; }
    __syncthreads();
    s = sb[0] + sb[1] + sb[2] + sb[3];
    ss = ssb[0] + ssb[1] + ssb[2] + ssb[3];
    const float mean = s * (1.f / 768.f);
    float var = ss * (1.f / 768.f) - mean * mean;
    if (var < 0.f) var = 0.f;
    const float invs = rsqrtf(var + 1e-5f);
    if (bf16out) {
        unsigned short* o = (unsigned short*)out;
#pragma unroll
        for (int j = 0; j < 3; ++j) {
            int c = tid + j * 256;
            o[(size_t)row * HID_ + c] = f2bf((vals[j] - mean) * invs * g[c] + bta[c]);
        }
    } else {
        float* o = (float*)out;
#pragma unroll
        for (int j = 0; j < 3; ++j) {
            int c = tid + j * 256;
            o[(size_t)row * HID_ + c] = (vals[j] - mean) * invs * g[c] + bta[c];
        }
    }
}

// ---------------------------------------------------------------------------
extern "C" void kernel_launch(void* const* d_in, const int* in_sizes, int n_in,
                              void* d_out, int out_size, void* d_ws, size_t ws_size,
                              hipStream_t stream) {
    const float* inp     = (const float*)d_in[0];
    const int*   seq_len = (const int*)d_in[1];
    const int*   lex_num = (const int*)d_in[2];
    const float* rel     = (const float*)d_in[3];
    const float* Wq = (const float*)d_in[4];
    const float* bq = (const float*)d_in[5];
    const float* Wk = (const float*)d_in[6];
    const float* bk = (const float*)d_in[7];
    const float* Wv = (const float*)d_in[8];
    const float* bv = (const float*)d_in[9];
    const float* Wo = (const float*)d_in[10];
    const float* bo = (const float*)d_in[11];
    const float* W0 = (const float*)d_in[12];
    const float* b0 = (const float*)d_in[13];
    const float* W1 = (const float*)d_in[14];
    const float* b1 = (const float*)d_in[15];
    const float* ln_g = (const float*)d_in[16];
    const float* ln_b = (const float*)d_in[17];
    float* out = (float*)d_out;

    // ---- workspace carve (bytes) ----
    char* W = (char*)d_ws;
    const size_t WT_SZ = (size_t)HID_ * HID_ * 2;
    unsigned short* Wt[6];
    for (int i = 0; i < 6; ++i) Wt[i] = (unsigned short*)(W + i * WT_SZ);
    size_t off = 6 * WT_SZ;
    const size_t TOK_BF = (size_t)B_ * L_ * HID_ * 2;
    unsigned short* qb  = (unsigned short*)(W + off); off += TOK_BF;
    unsigned short* kb  = (unsigned short*)(W + off); off += TOK_BF;
    unsigned short* vtb = (unsigned short*)(W + off); off += TOK_BF;
    unsigned short* Eb  = (unsigned short*)(W + off); off += TOK_BF;
    float* Fbuf = (float*)(W + off);

    unsigned short* Xb   = Eb;
    unsigned short* ctxb = Eb;
    unsigned short* y2b  = vtb;
    unsigned short* hb   = qb;

    convert_x_kernel<<<dim3(3072), dim3(256), 0, stream>>>(inp, Xb, (B_ * L_ * HID_) / 4);

    {
        WArgs wa;
        const float* ws_[6] = {Wq, Wk, Wv, Wo, W0, W1};
        for (int i = 0; i < 6; ++i) { wa.w[i] = ws_[i]; wa.wt[i] = Wt[i]; }
        transpose_w_kernel<<<dim3(12, 12, 6), dim3(256), 0, stream>>>(wa);
    }

    {
        GemmArgs ga;
        ga.j[0] = {Xb, Wt[0], bq, (void*)qb,  1, 0, SCALE_};
        ga.j[1] = {Xb, Wt[1], bk, (void*)kb,  1, 0, 1.f};
        ga.j[2] = {Xb, Wt[2], bv, (void*)vtb, 2, 0, 1.f};
        gemm_bf16_kernel<<<dim3(32, 6, 3), dim3(256), 0, stream>>>(ga);
    }

    attn_mfma_kernel<<<dim3(16, 48), dim3(256), 0, stream>>>(
        qb, kb, vtb, rel, seq_len, lex_num, ctxb);

    {
        GemmArgs ga;
        ga.j[0] = {ctxb, Wt[3], bo, (void*)Fbuf, 0, 0, 1.f};
        gemm_bf16_kernel<<<dim3(32, 6, 1), dim3(256), 0, stream>>>(ga);
    }
    ln2_kernel<<<dim3(4096), dim3(256), 0, stream>>>(Fbuf, ln_g, ln_b, (void*)y2b, 1);
    {
        GemmArgs ga;
        ga.j[0] = {y2b, Wt[4], b0, (void*)hb, 1, 1, 1.f};
        gemm_bf16_kernel<<<dim3(32, 6, 1), dim3(256), 0, stream>>>(ga);
    }
    {
        GemmArgs ga;
        ga.j[0] = {hb, Wt[5], b1, (void*)Fbuf, 0, 0, 1.f};
        gemm_bf16_kernel<<<dim3(32, 6, 1), dim3(256), 0, stream>>>(ga);
    }
    ln2_kernel<<<dim3(4096), dim3(256), 0, stream>>>(Fbuf, ln_g, ln_b, (void*)out, 0);
}

// Round 6
// 132.758 us; speedup vs baseline: 1.3974x; 1.1880x over previous
//
#include <hip/hip_runtime.h>
#include <math.h>

#define B_   4
#define L_   1024
#define HID_ 768
#define NH_  12
#define D_   64
#define SCALE_ 0.125f
#define NEGV (-1e15f)

typedef __attribute__((ext_vector_type(4))) float  f32x4;
typedef __attribute__((ext_vector_type(8))) __bf16 bf16x8;
typedef __attribute__((ext_vector_type(8))) unsigned short ushort8v;
typedef __attribute__((ext_vector_type(4))) unsigned short ushort4v;

typedef const __attribute__((address_space(1))) unsigned int* gas1_t;
typedef __attribute__((address_space(3))) unsigned int*       las3_t;
#define GLDS16(g, l) __builtin_amdgcn_global_load_lds((gas1_t)(g), (las3_t)(l), 16, 0, 0)

static __device__ __forceinline__ unsigned short f2bf(float f) {
    unsigned int u = __builtin_bit_cast(unsigned int, f);
    u += 0x7fffu + ((u >> 16) & 1u);           // RNE
    return (unsigned short)(u >> 16);
}

// ---------------------------------------------------------------------------
// inp f32 -> bf16
// ---------------------------------------------------------------------------
__global__ __launch_bounds__(256) void convert_x_kernel(
    const float* __restrict__ in, unsigned short* __restrict__ out, int n4)
{
    int i = blockIdx.x * 256 + threadIdx.x;
    if (i < n4) {
        float4 v = reinterpret_cast<const float4*>(in)[i];
        ushort4v o;
        o.x = f2bf(v.x); o.y = f2bf(v.y); o.z = f2bf(v.z); o.w = f2bf(v.w);
        reinterpret_cast<ushort4v*>(out)[i] = o;
    }
}

// ---------------------------------------------------------------------------
// W f32 [768 in][768 out] -> Wt bf16 [768 out][768 in]. grid (12,12,6).
// ---------------------------------------------------------------------------
struct WArgs { const float* w[6]; unsigned short* wt[6]; };

__global__ __launch_bounds__(256) void transpose_w_kernel(WArgs a)
{
    const float* W = a.w[blockIdx.z];
    unsigned short* Wt = a.wt[blockIdx.z];
    __shared__ float t[64][65];
    const int tid = threadIdx.x;
    const int lr = tid >> 2, lc4 = (tid & 3) * 16;
    const int r0 = blockIdx.y * 64, c0 = blockIdx.x * 64;
#pragma unroll
    for (int j = 0; j < 4; ++j) {
        float4 v = *reinterpret_cast<const float4*>(&W[(size_t)(r0 + lr) * HID_ + c0 + lc4 + j * 4]);
        t[lr][lc4 + j * 4 + 0] = v.x;
        t[lr][lc4 + j * 4 + 1] = v.y;
        t[lr][lc4 + j * 4 + 2] = v.z;
        t[lr][lc4 + j * 4 + 3] = v.w;
    }
    __syncthreads();
    unsigned short tmp[16];
#pragma unroll
    for (int j = 0; j < 16; ++j) tmp[j] = f2bf(t[lc4 + j][lr]);
    unsigned short* dst = &Wt[(size_t)(c0 + lr) * HID_ + r0 + lc4];
    *reinterpret_cast<ushort8v*>(dst)     = *reinterpret_cast<ushort8v*>(&tmp[0]);
    *reinterpret_cast<ushort8v*>(dst + 8) = *reinterpret_cast<ushort8v*>(&tmp[8]);
}

// ---------------------------------------------------------------------------
// bf16 GEMM: C[4096,768] = A @ Wt^T + bias. Tile 64x128, BK=64, 4 waves,
// wave w owns 64x32 (frags 4x2). Grid (64, 6, z). 24.5 KB LDS.
// mode 0: f32 C ; mode 1: bf16 C ; mode 2: bf16 Vt[(b*768+n)*1024+l]
// ---------------------------------------------------------------------------
struct GemmJob {
    const unsigned short* A;
    const unsigned short* Wt;
    const float* bias;
    void* C;
    int mode;
    int relu;
    float scale;
};
struct GemmArgs { GemmJob j[3]; };

__global__ __launch_bounds__(256, 4) void gemm_bf16_kernel(GemmArgs args)
{
    const GemmJob jb = args.j[blockIdx.z];
    __shared__ unsigned short As[64 * 64];    // [64][64] bf16, chunk-XOR-swizzled
    __shared__ unsigned short Bs[128 * 64];

    const int tid = threadIdx.x;
    const int w = tid >> 6, lane = tid & 63, g = lane >> 4, lq = lane & 15;
    const int m0 = blockIdx.x * 64, n0 = blockIdx.y * 128;

    f32x4 acc[4][2];
#pragma unroll
    for (int i = 0; i < 4; ++i)
#pragma unroll
        for (int j = 0; j < 2; ++j) acc[i][j] = (f32x4){0.f, 0.f, 0.f, 0.f};

    // staging: chunk c_lin = batch*256 + tid ; r = batch*32 + (tid>>3) ;
    // k-chunk kq = (tid&7) ^ ((tid>>3)&7)  (same for all batches)
    const int sr = tid >> 3;
    const int kq = ((tid & 7) ^ (sr & 7)) * 8;
    const unsigned short* Ap0 = jb.A  + (size_t)(m0 + sr) * HID_ + kq;
    const unsigned short* Ap1 = jb.A  + (size_t)(m0 + 32 + sr) * HID_ + kq;
    const unsigned short* Bp0 = jb.Wt + (size_t)(n0 + sr) * HID_ + kq;
    const unsigned short* Bp1 = jb.Wt + (size_t)(n0 + 32 + sr) * HID_ + kq;
    const unsigned short* Bp2 = jb.Wt + (size_t)(n0 + 64 + sr) * HID_ + kq;
    const unsigned short* Bp3 = jb.Wt + (size_t)(n0 + 96 + sr) * HID_ + kq;
    char* AsB = (char*)As;
    char* BsB = (char*)Bs;
    const int wb = w * 1024;

    for (int k0 = 0; k0 < HID_; k0 += 64) {
        __syncthreads();
        GLDS16(Ap0 + k0, AsB + wb);
        GLDS16(Ap1 + k0, AsB + 4096 + wb);
        GLDS16(Bp0 + k0, BsB + wb);
        GLDS16(Bp1 + k0, BsB + 4096 + wb);
        GLDS16(Bp2 + k0, BsB + 8192 + wb);
        GLDS16(Bp3 + k0, BsB + 12288 + wb);
        __syncthreads();

#pragma unroll
        for (int ks = 0; ks < 2; ++ks) {
            bf16x8 af[4], bf[2];
#pragma unroll
            for (int mi = 0; mi < 4; ++mi) {
                int row = mi * 16 + lq;
                int c = (ks * 4 + g) ^ (row & 7);
                af[mi] = *reinterpret_cast<const bf16x8*>(&As[row * 64 + c * 8]);
            }
#pragma unroll
            for (int ni = 0; ni < 2; ++ni) {
                int row = w * 32 + ni * 16 + lq;
                int c = (ks * 4 + g) ^ (row & 7);
                bf[ni] = *reinterpret_cast<const bf16x8*>(&Bs[row * 64 + c * 8]);
            }
            __builtin_amdgcn_s_setprio(1);
#pragma unroll
            for (int mi = 0; mi < 4; ++mi)
#pragma unroll
                for (int ni = 0; ni < 2; ++ni)
                    acc[mi][ni] = __builtin_amdgcn_mfma_f32_16x16x32_bf16(
                        af[mi], bf[ni], acc[mi][ni], 0, 0, 0);
            __builtin_amdgcn_s_setprio(0);
        }
    }

    float bcol[2];
#pragma unroll
    for (int ni = 0; ni < 2; ++ni) bcol[ni] = jb.bias[n0 + w * 32 + ni * 16 + lq];

#pragma unroll
    for (int mi = 0; mi < 4; ++mi) {
#pragma unroll
        for (int ni = 0; ni < 2; ++ni) {
            const int n = n0 + w * 32 + ni * 16 + lq;
            float v[4];
#pragma unroll
            for (int r = 0; r < 4; ++r) {
                float x = (acc[mi][ni][r] + bcol[ni]) * jb.scale;
                if (jb.relu) x = fmaxf(x, 0.f);
                v[r] = x;
            }
            const int mbase = m0 + mi * 16 + 4 * g;
            if (jb.mode == 0) {
                float* C = (float*)jb.C;
#pragma unroll
                for (int r = 0; r < 4; ++r)
                    C[(size_t)(mbase + r) * HID_ + n] = v[r];
            } else if (jb.mode == 1) {
                unsigned short* C = (unsigned short*)jb.C;
#pragma unroll
                for (int r = 0; r < 4; ++r)
                    C[(size_t)(mbase + r) * HID_ + n] = f2bf(v[r]);
            } else {
                unsigned short* C = (unsigned short*)jb.C;
                const int bb = mbase >> 10, ltok = mbase & 1023;
                ushort4v o;
                o.x = f2bf(v[0]); o.y = f2bf(v[1]); o.z = f2bf(v[2]); o.w = f2bf(v[3]);
                *reinterpret_cast<ushort4v*>(&C[(size_t)(bb * HID_ + n) * L_ + ltok]) = o;
            }
        }
    }
}

// ---------------------------------------------------------------------------
// Flash attention, bf16 MFMA, DEPTH-2 register prefetch:
//  - tile-skip via nkt; K/V double-buffered LDS; one barrier per tile
//  - reg sets A/B hold tiles t and t+1; loads for t+2 issued at tile t
//    (load->use distance = 2 full tiles of compute)
//  - rel prefetched 2-deep in registers (consumed before overwrite)
// Q pre-scaled, in registers. Vt layout [b][h][d][l]. Grid (16, 48).
// ---------------------------------------------------------------------------
__global__ __launch_bounds__(256, 3) void attn_mfma_kernel(
    const unsigned short* __restrict__ Qb, const unsigned short* __restrict__ Kb,
    const unsigned short* __restrict__ Vtb, const float* __restrict__ rel,
    const int* __restrict__ seq_len, const int* __restrict__ lex_num,
    unsigned short* __restrict__ ctx)
{
    const int qt = blockIdx.x, bh = blockIdx.y;
    const int b = bh / NH_, h = bh % NH_;
    const int q0 = qt * 64;
    const int sl = seq_len[b] + lex_num[0];
    const int nkt = (sl + 63) >> 6;

    __shared__ unsigned short Ks0[64 * 72], Ks1[64 * 72];
    __shared__ unsigned short Vs0[64 * 72], Vs1[64 * 72];
    __shared__ unsigned short Ps[64 * 72];

    const int tid = threadIdx.x;
    const int w = tid >> 6, lane = tid & 63, g = lane >> 4, lq = lane & 15;
    const int r0 = tid >> 3, cc0 = tid & 7;
    const int r1 = 32 + r0;

    const unsigned short* Kbase = Kb  + (size_t)(b * L_) * HID_ + h * D_;
    const unsigned short* Vbase = Vtb + (size_t)(b * HID_ + h * D_) * L_;
    const float* relbase = rel + (size_t)bh * (L_ * L_) + (size_t)(q0 + w * 16 + 4 * g) * L_ + lq;

    // Q A-fragments in registers
    bf16x8 aq[2];
#pragma unroll
    for (int ks = 0; ks < 2; ++ks)
        aq[ks] = *reinterpret_cast<const bf16x8*>(
            &Qb[(size_t)(b * L_ + q0 + w * 16 + lq) * HID_ + h * D_ + ks * 32 + g * 8]);

    f32x4 acc[4];
    float m_r[4], l_r[4];
#pragma unroll
    for (int i = 0; i < 4; ++i) {
        acc[i] = (f32x4){0.f, 0.f, 0.f, 0.f};
        m_r[i] = -3e38f; l_r[i] = 0.f;
    }

    ushort8v kA0, kA1, vA0, vA1, kB0, kB1, vB0, vB1;
    float relA[16], relB[16];

    auto load_set = [&](int kt_, ushort8v& K0, ushort8v& K1, ushort8v& V0,
                        ushort8v& V1, float (&R)[16]) {
        const int k0 = kt_ * 64;
        K0 = *reinterpret_cast<const ushort8v*>(&Kbase[(size_t)(k0 + r0) * HID_ + cc0 * 8]);
        K1 = *reinterpret_cast<const ushort8v*>(&Kbase[(size_t)(k0 + r1) * HID_ + cc0 * 8]);
        V0 = *reinterpret_cast<const ushort8v*>(&Vbase[(size_t)r0 * L_ + k0 + cc0 * 8]);
        V1 = *reinterpret_cast<const ushort8v*>(&Vbase[(size_t)r1 * L_ + k0 + cc0 * 8]);
#pragma unroll
        for (int ni = 0; ni < 4; ++ni)
#pragma unroll
            for (int r = 0; r < 4; ++r)
                R[ni * 4 + r] = relbase[(size_t)r * L_ + k0 + ni * 16];
    };

    auto body = [&](int kt_, ushort8v& K0, ushort8v& K1, ushort8v& V0, ushort8v& V1,
                    float (&R)[16], unsigned short* KsC, unsigned short* VsC) {
        const int k0 = kt_ * 64;
        // write staged regs into this parity's LDS buffer
        *reinterpret_cast<ushort8v*>(&KsC[r0 * 72 + cc0 * 8]) = K0;
        *reinterpret_cast<ushort8v*>(&KsC[r1 * 72 + cc0 * 8]) = K1;
        *reinterpret_cast<ushort8v*>(&VsC[r0 * 72 + cc0 * 8]) = V0;
        *reinterpret_cast<ushort8v*>(&VsC[r1 * 72 + cc0 * 8]) = V1;
        __syncthreads();

        // K/V prefetch for tile kt_+2 into the just-freed reg set
        {
            int tn = kt_ + 2; if (tn > nkt - 1) tn = nkt - 1;
            const int kn = tn * 64;
            K0 = *reinterpret_cast<const ushort8v*>(&Kbase[(size_t)(kn + r0) * HID_ + cc0 * 8]);
            K1 = *reinterpret_cast<const ushort8v*>(&Kbase[(size_t)(kn + r1) * HID_ + cc0 * 8]);
            V0 = *reinterpret_cast<const ushort8v*>(&Vbase[(size_t)r0 * L_ + kn + cc0 * 8]);
            V1 = *reinterpret_cast<const ushort8v*>(&Vbase[(size_t)r1 * L_ + kn + cc0 * 8]);
        }

        // S strip = Q strip @ K^T
        f32x4 s[4];
#pragma unroll
        for (int ni = 0; ni < 4; ++ni) s[ni] = (f32x4){0.f, 0.f, 0.f, 0.f};
        __builtin_amdgcn_s_setprio(1);
#pragma unroll
        for (int ks = 0; ks < 2; ++ks) {
#pragma unroll
            for (int ni = 0; ni < 4; ++ni) {
                bf16x8 bk = *reinterpret_cast<const bf16x8*>(
                    &KsC[(ni * 16 + lq) * 72 + ks * 32 + g * 8]);
                s[ni] = __builtin_amdgcn_mfma_f32_16x16x32_bf16(aq[ks], bk, s[ni], 0, 0, 0);
            }
        }
        __builtin_amdgcn_s_setprio(0);

        // + rel bias (consume R), mask
        float sv[4][4];
#pragma unroll
        for (int ni = 0; ni < 4; ++ni) {
            const int col = k0 + ni * 16 + lq;
            const bool ok = col < sl;
#pragma unroll
            for (int r = 0; r < 4; ++r)
                sv[ni][r] = ok ? (s[ni][r] + R[ni * 4 + r]) : NEGV;
        }

        // rel prefetch for tile kt_+2 (R now free)
        {
            int tn = kt_ + 2; if (tn > nkt - 1) tn = nkt - 1;
            const int kn = tn * 64;
#pragma unroll
            for (int ni = 0; ni < 4; ++ni)
#pragma unroll
                for (int r = 0; r < 4; ++r)
                    R[ni * 4 + r] = relbase[(size_t)r * L_ + kn + ni * 16];
        }

        // online softmax per row (16 lanes share a row)
#pragma unroll
        for (int r = 0; r < 4; ++r) {
            float rm = fmaxf(fmaxf(sv[0][r], sv[1][r]), fmaxf(sv[2][r], sv[3][r]));
            rm = fmaxf(rm, __shfl_xor(rm, 1, 16));
            rm = fmaxf(rm, __shfl_xor(rm, 2, 16));
            rm = fmaxf(rm, __shfl_xor(rm, 4, 16));
            rm = fmaxf(rm, __shfl_xor(rm, 8, 16));
            float mn = fmaxf(m_r[r], rm);
            float sc = __expf(m_r[r] - mn);
            float p[4], rs = 0.f;
#pragma unroll
            for (int ni = 0; ni < 4; ++ni) {
                p[ni] = __expf(sv[ni][r] - mn);
                rs += p[ni];
            }
            rs += __shfl_xor(rs, 1, 16);
            rs += __shfl_xor(rs, 2, 16);
            rs += __shfl_xor(rs, 4, 16);
            rs += __shfl_xor(rs, 8, 16);
            l_r[r] = l_r[r] * sc + rs;
            m_r[r] = mn;
#pragma unroll
            for (int ni = 0; ni < 4; ++ni) {
                acc[ni][r] *= sc;
                Ps[(w * 16 + 4 * g + r) * 72 + ni * 16 + lq] = f2bf(p[ni]);
            }
        }

        // O strip += P strip @ V tile (own-wave P strip, same-wave lgkm order)
        __builtin_amdgcn_s_setprio(1);
#pragma unroll
        for (int ks = 0; ks < 2; ++ks) {
            bf16x8 ap = *reinterpret_cast<const bf16x8*>(
                &Ps[(w * 16 + lq) * 72 + ks * 32 + g * 8]);
#pragma unroll
            for (int ni = 0; ni < 4; ++ni) {
                bf16x8 bv = *reinterpret_cast<const bf16x8*>(
                    &VsC[(ni * 16 + lq) * 72 + ks * 32 + g * 8]);
                acc[ni] = __builtin_amdgcn_mfma_f32_16x16x32_bf16(ap, bv, acc[ni], 0, 0, 0);
            }
        }
        __builtin_amdgcn_s_setprio(0);
    };

    // prologue: tiles 0 and 1 into reg sets A and B
    load_set(0, kA0, kA1, vA0, vA1, relA);
    load_set(nkt > 1 ? 1 : 0, kB0, kB1, vB0, vB1, relB);

    for (int kt = 0; kt < nkt; kt += 2) {
        body(kt, kA0, kA1, vA0, vA1, relA, Ks0, Vs0);
        if (kt + 1 < nkt)
            body(kt + 1, kB0, kB1, vB0, vB1, relB, Ks1, Vs1);
    }

    // epilogue
    float inv[4];
#pragma unroll
    for (int r = 0; r < 4; ++r) inv[r] = 1.f / l_r[r];
#pragma unroll
    for (int ni = 0; ni < 4; ++ni)
#pragma unroll
        for (int r = 0; r < 4; ++r)
            ctx[(size_t)(b * L_ + q0 + w * 16 + 4 * g + r) * HID_ + h * D_ + ni * 16 + lq] =
                f2bf(acc[ni][r] * inv[r]);
}

// ---------------------------------------------------------------------------
// LayerNorm(2*x) over rows of 768; out f32 or bf16.
// ---------------------------------------------------------------------------
__global__ __launch_bounds__(256) void ln2_kernel(
    const float* __restrict__ in, const float* __restrict__ g,
    const float* __restrict__ bta, void* __restrict__ out, int bf16out)
{
    const int row = blockIdx.x;
    const float* x = in + (size_t)row * HID_;
    const int tid = threadIdx.x;

    float vals[3];
    float s = 0.f, ss = 0.f;
#pragma unroll
    for (int j = 0; j < 3; ++j) {
        float t = 2.f * x[tid + j * 256];
        vals[j] = t;
        s += t;
        ss += t * t;
    }
#pragma unroll
    for (int m = 1; m < 64; m <<= 1) {
        s += __shfl_xor(s, m, 64);
        ss += __shfl_xor(ss, m, 64);
    }
    __shared__ float sb[4], ssb[4];
    if ((tid & 63) == 0) { sb[tid >> 6] = s; ssb[tid >> 6] = ss; }
    __syncthreads();
    s = sb[0] + sb[1] + sb[2] + sb[3];
    ss = ssb[0] + ssb[1] + ssb[2] + ssb[3];
    const float mean = s * (1.f / 768.f);
    float var = ss * (1.f / 768.f) - mean * mean;
    if (var < 0.f) var = 0.f;
    const float invs = rsqrtf(var + 1e-5f);
    if (bf16out) {
        unsigned short* o = (unsigned short*)out;
#pragma unroll
        for (int j = 0; j < 3; ++j) {
            int c = tid + j * 256;
            o[(size_t)row * HID_ + c] = f2bf((vals[j] - mean) * invs * g[c] + bta[c]);
        }
    } else {
        float* o = (float*)out;
#pragma unroll
        for (int j = 0; j < 3; ++j) {
            int c = tid + j * 256;
            o[(size_t)row * HID_ + c] = (vals[j] - mean) * invs * g[c] + bta[c];
        }
    }
}

// ---------------------------------------------------------------------------
extern "C" void kernel_launch(void* const* d_in, const int* in_sizes, int n_in,
                              void* d_out, int out_size, void* d_ws, size_t ws_size,
                              hipStream_t stream) {
    const float* inp     = (const float*)d_in[0];
    const int*   seq_len = (const int*)d_in[1];
    const int*   lex_num = (const int*)d_in[2];
    const float* rel     = (const float*)d_in[3];
    const float* Wq = (const float*)d_in[4];
    const float* bq = (const float*)d_in[5];
    const float* Wk = (const float*)d_in[6];
    const float* bk = (const float*)d_in[7];
    const float* Wv = (const float*)d_in[8];
    const float* bv = (const float*)d_in[9];
    const float* Wo = (const float*)d_in[10];
    const float* bo = (const float*)d_in[11];
    const float* W0 = (const float*)d_in[12];
    const float* b0 = (const float*)d_in[13];
    const float* W1 = (const float*)d_in[14];
    const float* b1 = (const float*)d_in[15];
    const float* ln_g = (const float*)d_in[16];
    const float* ln_b = (const float*)d_in[17];
    float* out = (float*)d_out;

    // ---- workspace carve (bytes) ----
    char* W = (char*)d_ws;
    const size_t WT_SZ = (size_t)HID_ * HID_ * 2;
    unsigned short* Wt[6];
    for (int i = 0; i < 6; ++i) Wt[i] = (unsigned short*)(W + i * WT_SZ);
    size_t off = 6 * WT_SZ;
    const size_t TOK_BF = (size_t)B_ * L_ * HID_ * 2;
    unsigned short* qb  = (unsigned short*)(W + off); off += TOK_BF;
    unsigned short* kb  = (unsigned short*)(W + off); off += TOK_BF;
    unsigned short* vtb = (unsigned short*)(W + off); off += TOK_BF;
    unsigned short* Eb  = (unsigned short*)(W + off); off += TOK_BF;
    float* Fbuf = (float*)(W + off);

    unsigned short* Xb   = Eb;
    unsigned short* ctxb = Eb;
    unsigned short* y2b  = vtb;
    unsigned short* hb   = qb;

    convert_x_kernel<<<dim3(3072), dim3(256), 0, stream>>>(inp, Xb, (B_ * L_ * HID_) / 4);

    {
        WArgs wa;
        const float* ws_[6] = {Wq, Wk, Wv, Wo, W0, W1};
        for (int i = 0; i < 6; ++i) { wa.w[i] = ws_[i]; wa.wt[i] = Wt[i]; }
        transpose_w_kernel<<<dim3(12, 12, 6), dim3(256), 0, stream>>>(wa);
    }

    {
        GemmArgs ga;
        ga.j[0] = {Xb, Wt[0], bq, (void*)qb,  1, 0, SCALE_};
        ga.j[1] = {Xb, Wt[1], bk, (void*)kb,  1, 0, 1.f};
        ga.j[2] = {Xb, Wt[2], bv, (void*)vtb, 2, 0, 1.f};
        gemm_bf16_kernel<<<dim3(64, 6, 3), dim3(256), 0, stream>>>(ga);
    }

    attn_mfma_kernel<<<dim3(16, 48), dim3(256), 0, stream>>>(
        qb, kb, vtb, rel, seq_len, lex_num, ctxb);

    {
        GemmArgs ga;
        ga.j[0] = {ctxb, Wt[3], bo, (void*)Fbuf, 0, 0, 1.f};
        gemm_bf16_kernel<<<dim3(64, 6, 1), dim3(256), 0, stream>>>(ga);
    }
    ln2_kernel<<<dim3(4096), dim3(256), 0, stream>>>(Fbuf, ln_g, ln_b, (void*)y2b, 1);
    {
        GemmArgs ga;
        ga.j[0] = {y2b, Wt[4], b0, (void*)hb, 1, 1, 1.f};
        gemm_bf16_kernel<<<dim3(64, 6, 1), dim3(256), 0, stream>>>(ga);
    }
    {
        GemmArgs ga;
        ga.j[0] = {hb, Wt[5], b1, (void*)Fbuf, 0, 0, 1.f};
        gemm_bf16_kernel<<<dim3(64, 6, 1), dim3(256), 0, stream>>>(ga);
    }
    ln2_kernel<<<dim3(4096), dim3(256), 0, stream>>>(Fbuf, ln_g, ln_b, (void*)out, 0);
}